// Round 1
// baseline (933.483 us; speedup 1.0000x reference)
//
#include <hip/hip_runtime.h>
#include <hip/hip_bf16.h>

// HINGCN_GS: f32 implementation.
// Pipeline per metapath mp:
//   1. F = relu(feats[gather(ids|n0|n1)] @ Wprep)        [113664,128]
//   2. S = F0 @ WsP0   (slf, no relu)                     [1024,256]
//   3. G0 = agg(F1, ed0(gather), S)                       [1024,256]
//   4. S = F1 @ WsP0                                      [10240,256]
//   5. G1 = agg(F2, ed1(gather), S)                       [10240,256]
//   6. EDU = relu([repeat(G0,10), G1, ed0] @ Wedge0[mp])  [10240,32]
//   7. S = G0 @ WsP1                                      [1024,256]
//   8. OB[mp] = agg(G1, EDU, S)                           [1024,256]
// Final: metapath attention + normalize + logits.
// Weights pre-permuted once: Wn[mp,h,K,O] -> WnP[mp][K][h*32+o].

#define DEV __device__ __forceinline__

DEV void fma4(float4& a, float s, const float4& w) {
  a.x = fmaf(s, w.x, a.x); a.y = fmaf(s, w.y, a.y);
  a.z = fmaf(s, w.z, a.z); a.w = fmaf(s, w.w, a.w);
}

// ---------------- weight permute (both mps, one launch) ----------------
__global__ __launch_bounds__(256) void permute_kernel(
    const float* __restrict__ Ws0, const float* __restrict__ Wn0, const float* __restrict__ We0,
    const float* __restrict__ Ws1, const float* __restrict__ Wn1, const float* __restrict__ We1,
    float* __restrict__ WsP0, float* __restrict__ WnP0, float* __restrict__ WeP0,
    float* __restrict__ WsP1, float* __restrict__ WnP1, float* __restrict__ WeP1)
{
  int i = blockIdx.x * 256 + threadIdx.x;
  if (i >= 2 * 212992) return;
  int mp = i / 212992, r = i % 212992;
  const float* src; float* dst; int Kd, li;
  if (r < 32768)       { src = Ws0; dst = WsP0; Kd = 128; li = r; }
  else if (r < 65536)  { src = Wn0; dst = WnP0; Kd = 128; li = r - 32768; }
  else if (r < 73728)  { src = We0; dst = WeP0; Kd = 32;  li = r - 65536; }
  else if (r < 139264) { src = Ws1; dst = WsP1; Kd = 256; li = r - 73728; }
  else if (r < 204800) { src = Wn1; dst = WnP1; Kd = 256; li = r - 139264; }
  else                 { src = We1; dst = WeP1; Kd = 32;  li = r - 204800; }
  int d = li >> 8, j = li & 255;
  int h = j >> 5, o = j & 31;
  dst[(size_t)mp * Kd * 256 + li] = src[(((size_t)mp * 8 + h) * Kd + d) * 32 + o];
}

// ---------------- generic small GEMM: out[M,N] = (relu?)(X[M,K] @ W[K,N]) ----------------
// Thread computes a 4x4 tile. A staged in LDS; inner reads are ds_read_b128
// broadcasts (wave-uniform or 2-way -> conflict-free). W streamed coalesced (L2-hot).
template<int N, int K, bool GATHER, bool RELU>
__global__ __launch_bounds__(256) void gemm_k(
    const float* __restrict__ X,
    const int* __restrict__ i0, const int* __restrict__ i1, const int* __restrict__ i2,
    const float* __restrict__ W, float* __restrict__ out)
{
  constexpr int CG = N / 4, RG = 256 / CG, BM = RG * 4, K4 = K / 4;
  __shared__ float A[BM * K];
  int t = threadIdx.x;
  int r0 = blockIdx.x * BM;
  float4* A4 = (float4*)A;
  if (GATHER) {
    for (int e = t; e < BM * K4; e += 256) {
      int rr = e / K4, c = e - rr * K4;
      int gr = r0 + rr;
      int idx = (gr < 1024) ? i0[gr] : ((gr < 11264) ? i1[gr - 1024] : i2[gr - 11264]);
      A4[e] = ((const float4*)X)[(size_t)idx * K4 + c];
    }
  } else {
    const float4* X4 = (const float4*)(X + (size_t)r0 * K);
    for (int e = t; e < BM * K4; e += 256) A4[e] = X4[e];
  }
  __syncthreads();
  int cg = t % CG, rg = t / CG;
  int c0 = cg * 4;
  const float* Arow = A + rg * 4 * K;
  float4 acc[4];
#pragma unroll
  for (int r = 0; r < 4; ++r) acc[r] = make_float4(0.f, 0.f, 0.f, 0.f);
  for (int k = 0; k < K; k += 4) {
    float4 w0 = *(const float4*)&W[(k + 0) * N + c0];
    float4 w1 = *(const float4*)&W[(k + 1) * N + c0];
    float4 w2 = *(const float4*)&W[(k + 2) * N + c0];
    float4 w3 = *(const float4*)&W[(k + 3) * N + c0];
#pragma unroll
    for (int r = 0; r < 4; ++r) {
      float4 a = *(const float4*)&Arow[r * K + k];
      fma4(acc[r], a.x, w0); fma4(acc[r], a.y, w1);
      fma4(acc[r], a.z, w2); fma4(acc[r], a.w, w3);
    }
  }
#pragma unroll
  for (int r = 0; r < 4; ++r) {
    float4 v = acc[r];
    if (RELU) { v.x = fmaxf(v.x, 0.f); v.y = fmaxf(v.y, 0.f); v.z = fmaxf(v.z, 0.f); v.w = fmaxf(v.w, 0.f); }
    *(float4*)&out[(size_t)(r0 + rg * 4 + r) * N + c0] = v;
  }
}

// ---------------- head aggregator ----------------
// Block = 4 groups (4 waves, one group per wave). Thread owns 4 output cols,
// keeps all 10 per-s accumulators in registers; mean-over-s + slf + relu fused.
template<int K>
__global__ __launch_bounds__(256) void agg_kernel(
    const float* __restrict__ neigh,   // [Ngroups*10, K]
    const float* __restrict__ edsrc,   // edge_emb (if eidx) else direct [Ngroups*10,32]
    const int* __restrict__ eidx,      // may be null
    const float* __restrict__ slf,     // [Ngroups,256]
    const float* __restrict__ WnP,     // [K,256]
    const float* __restrict__ WeP,     // [32,256]
    float* __restrict__ out)           // [Ngroups,256]
{
  __shared__ float NB[40 * K];
  __shared__ float EB[40 * 32];
  int t = threadIdx.x;
  int n0 = blockIdx.x * 4;
  {
    const float4* src4 = (const float4*)(neigh + (size_t)n0 * 10 * K);
    float4* nb4 = (float4*)NB;
    for (int e = t; e < 10 * K; e += 256) nb4[e] = src4[e];  // 40 rows contiguous
  }
  for (int e = t; e < 1280; e += 256) {
    int s = e >> 5, c = e & 31;
    int r = n0 * 10 + s;
    EB[e] = eidx ? edsrc[(size_t)eidx[r] * 32 + c] : edsrc[(size_t)r * 32 + c];
  }
  __syncthreads();
  int g = t >> 6, l = t & 63;   // g wave-uniform -> LDS reads below are broadcasts
  int c0 = l * 4;
  const float* NBg = NB + g * 10 * K;
  const float* EBg = EB + g * 10 * 32;
  float4 acc[10];
#pragma unroll
  for (int s = 0; s < 10; ++s) acc[s] = make_float4(0.f, 0.f, 0.f, 0.f);
  for (int k = 0; k < K; k += 4) {
    float4 w0 = *(const float4*)&WnP[(k + 0) * 256 + c0];
    float4 w1 = *(const float4*)&WnP[(k + 1) * 256 + c0];
    float4 w2 = *(const float4*)&WnP[(k + 2) * 256 + c0];
    float4 w3 = *(const float4*)&WnP[(k + 3) * 256 + c0];
#pragma unroll
    for (int s = 0; s < 10; ++s) {
      float4 a = *(const float4*)&NBg[s * K + k];
      fma4(acc[s], a.x, w0); fma4(acc[s], a.y, w1);
      fma4(acc[s], a.z, w2); fma4(acc[s], a.w, w3);
    }
  }
  for (int e = 0; e < 32; e += 4) {
    float4 w0 = *(const float4*)&WeP[(e + 0) * 256 + c0];
    float4 w1 = *(const float4*)&WeP[(e + 1) * 256 + c0];
    float4 w2 = *(const float4*)&WeP[(e + 2) * 256 + c0];
    float4 w3 = *(const float4*)&WeP[(e + 3) * 256 + c0];
#pragma unroll
    for (int s = 0; s < 10; ++s) {
      float4 a = *(const float4*)&EBg[s * 32 + e];
      fma4(acc[s], a.x, w0); fma4(acc[s], a.y, w1);
      fma4(acc[s], a.z, w2); fma4(acc[s], a.w, w3);
    }
  }
  float4 m = make_float4(0.f, 0.f, 0.f, 0.f);
#pragma unroll
  for (int s = 0; s < 10; ++s) {
    m.x += fmaxf(acc[s].x, 0.f); m.y += fmaxf(acc[s].y, 0.f);
    m.z += fmaxf(acc[s].z, 0.f); m.w += fmaxf(acc[s].w, 0.f);
  }
  int n = n0 + g;
  float4 sl = *(const float4*)&slf[(size_t)n * 256 + c0];
  float4 o;
  o.x = fmaxf(sl.x + m.x * 0.1f, 0.f);
  o.y = fmaxf(sl.y + m.y * 0.1f, 0.f);
  o.z = fmaxf(sl.z + m.z * 0.1f, 0.f);
  o.w = fmaxf(sl.w + m.w * 0.1f, 0.f);
  *(float4*)&out[(size_t)n * 256 + c0] = o;
}

// ---------------- edge update ----------------
// out[r,j] = relu(concat(g0[r/10], g1[r], ed0[r]) @ Wedge0[mp]) ; 8 rows/block.
__global__ __launch_bounds__(256) void edge_kernel(
    const float* __restrict__ g0, const float* __restrict__ g1,
    const float* __restrict__ edge_emb, const int* __restrict__ e0,
    const float* __restrict__ W,   // [544,32]
    float* __restrict__ out)       // [10240,32]
{
  __shared__ float R[8][544];
  int t = threadIdx.x;
  int r0 = blockIdx.x * 8;
  for (int e = t; e < 8 * 256; e += 256) {
    int rr = e >> 8, c = e & 255;
    R[rr][c]       = g0[(size_t)((r0 + rr) / 10) * 256 + c];
    R[rr][256 + c] = g1[(size_t)(r0 + rr) * 256 + c];
  }
  for (int e = t; e < 8 * 32; e += 256) {
    int rr = e >> 5, c = e & 31;
    R[rr][512 + c] = edge_emb[(size_t)e0[r0 + rr] * 32 + c];
  }
  __syncthreads();
  int j = t & 31, rr = t >> 5;
  float acc = 0.f;
  for (int k = 0; k < 544; k += 4) {
    float4 a = *(const float4*)&R[rr][k];
    acc = fmaf(a.x, W[(k + 0) * 32 + j], acc);
    acc = fmaf(a.y, W[(k + 1) * 32 + j], acc);
    acc = fmaf(a.z, W[(k + 2) * 32 + j], acc);
    acc = fmaf(a.w, W[(k + 3) * 32 + j], acc);
  }
  out[(size_t)(r0 + rr) * 32 + j] = fmaxf(acc, 0.f);
}

// ---------------- metapath attention + normalize + logits ----------------
__global__ __launch_bounds__(64) void final_kernel(
    const float* __restrict__ outb,   // [2,1024,256]
    const float* __restrict__ Wa,     // [256,64]
    const float* __restrict__ va,     // [64]
    const float* __restrict__ Wfc,    // [256,8]
    const float* __restrict__ bfc,    // [8]
    float* __restrict__ dout)         // logits 1024*8, then weights 2*1024
{
  __shared__ float aggv[256];
  int t = threadIdx.x;
  int n = blockIdx.x;
  const float* o0 = outb + (size_t)n * 256;
  const float* o1 = outb + (size_t)(1024 + n) * 256;
  float s[2];
#pragma unroll
  for (int mp = 0; mp < 2; ++mp) {
    const float* o = mp ? o1 : o0;
    float a = 0.f;
    for (int k = 0; k < 256; ++k) a = fmaf(o[k], Wa[k * 64 + t], a);
    float v = tanhf(a) * va[t];
#pragma unroll
    for (int msk = 32; msk; msk >>= 1) v += __shfl_xor(v, msk, 64);
    s[mp] = v;
  }
  float mx = fmaxf(s[0], s[1]);
  float ex0 = expf(s[0] - mx), ex1 = expf(s[1] - mx);
  float ise = 1.f / (ex0 + ex1);
  float w0 = ex0 * ise, w1 = ex1 * ise;
  float ss = 0.f;
  for (int k = t; k < 256; k += 64) {
    float av = fmaf(w0, o0[k], w1 * o1[k]);
    aggv[k] = av;
    ss = fmaf(av, av, ss);
  }
#pragma unroll
  for (int msk = 32; msk; msk >>= 1) ss += __shfl_xor(ss, msk, 64);
  float inv = 1.f / fmaxf(sqrtf(ss), 1e-12f);
  __syncthreads();
  if (t < 8) {
    float l = bfc[t];
    for (int k = 0; k < 256; ++k) l = fmaf(aggv[k] * inv, Wfc[k * 8 + t], l);
    dout[(size_t)n * 8 + t] = l;
  }
  if (t == 0) {
    dout[8192 + n] = w0;
    dout[8192 + 1024 + n] = w1;
  }
}

extern "C" void kernel_launch(void* const* d_in, const int* in_sizes, int n_in,
                              void* d_out, int out_size, void* d_ws, size_t ws_size,
                              hipStream_t stream) {
  (void)in_sizes; (void)n_in; (void)out_size;
  const int* ids = (const int*)d_in[0];
  const int* n0a[2] = {(const int*)d_in[1], (const int*)d_in[5]};
  const int* e0a[2] = {(const int*)d_in[2], (const int*)d_in[6]};
  const int* n1a[2] = {(const int*)d_in[3], (const int*)d_in[7]};
  const int* e1a[2] = {(const int*)d_in[4], (const int*)d_in[8]};
  const float* feats = (const float*)d_in[9];
  const float* eea[2] = {(const float*)d_in[10], (const float*)d_in[11]};
  const float* Wprep  = (const float*)d_in[12];
  const float* Ws0    = (const float*)d_in[13];
  const float* Wn0    = (const float*)d_in[14];
  const float* We0    = (const float*)d_in[15];
  const float* Ws1    = (const float*)d_in[16];
  const float* Wn1    = (const float*)d_in[17];
  const float* We1    = (const float*)d_in[18];
  const float* Wedge0 = (const float*)d_in[19];
  const float* Wa     = (const float*)d_in[20];
  const float* va     = (const float*)d_in[21];
  const float* Wfc    = (const float*)d_in[22];
  const float* bfc    = (const float*)d_in[23];
  float* out = (float*)d_out;

  float* w = (float*)d_ws;
  size_t off = 0;
  float* F    = w + off; off += (size_t)113664 * 128;   // f0|f1|f2 contiguous
  float* S    = w + off; off += (size_t)10240 * 256;    // slf scratch
  float* G0   = w + off; off += (size_t)1024 * 256;
  float* G1   = w + off; off += (size_t)10240 * 256;
  float* EDU  = w + off; off += (size_t)10240 * 32;
  float* OB   = w + off; off += (size_t)2 * 1024 * 256;
  float* WsP0 = w + off; off += (size_t)2 * 128 * 256;
  float* WnP0 = w + off; off += (size_t)2 * 128 * 256;
  float* WeP0 = w + off; off += (size_t)2 * 32 * 256;
  float* WsP1 = w + off; off += (size_t)2 * 256 * 256;
  float* WnP1 = w + off; off += (size_t)2 * 256 * 256;
  float* WeP1 = w + off; off += (size_t)2 * 32 * 256;
  if (ws_size < off * sizeof(float)) return;  // ~85.3 MB needed

  float* F0 = F;
  float* F1 = F + (size_t)1024 * 128;
  float* F2 = F + (size_t)11264 * 128;

  permute_kernel<<<1664, 256, 0, stream>>>(Ws0, Wn0, We0, Ws1, Wn1, We1,
                                           WsP0, WnP0, WeP0, WsP1, WnP1, WeP1);

  for (int mp = 0; mp < 2; ++mp) {
    // 1. prep all three hop levels (113664 rows, segments select index array)
    gemm_k<128, 128, true, true><<<3552, 256, 0, stream>>>(
        feats, ids, n0a[mp], n1a[mp], Wprep, F);
    // 2. slf for g0
    gemm_k<256, 128, false, false><<<64, 256, 0, stream>>>(
        F0, nullptr, nullptr, nullptr, WsP0 + mp * 32768, S);
    // 3. g0 = agg(f1, gather(ed0), slf)
    agg_kernel<128><<<256, 256, 0, stream>>>(
        F1, eea[mp], e0a[mp], S, WnP0 + mp * 32768, WeP0 + mp * 8192, G0);
    // 4. slf for g1
    gemm_k<256, 128, false, false><<<640, 256, 0, stream>>>(
        F1, nullptr, nullptr, nullptr, WsP0 + mp * 32768, S);
    // 5. g1 = agg(f2, gather(ed1), slf)
    agg_kernel<128><<<2560, 256, 0, stream>>>(
        F2, eea[mp], e1a[mp], S, WnP0 + mp * 32768, WeP0 + mp * 8192, G1);
    // 6. edge update
    edge_kernel<<<1280, 256, 0, stream>>>(
        G0, G1, eea[mp], e0a[mp], Wedge0 + (size_t)mp * 544 * 32, EDU);
    // 7. slf for layer-1
    gemm_k<256, 256, false, false><<<64, 256, 0, stream>>>(
        G0, nullptr, nullptr, nullptr, WsP1 + mp * 65536, S);
    // 8. layer-1 agg -> OB[mp]
    agg_kernel<256><<<256, 256, 0, stream>>>(
        G1, EDU, nullptr, S, WnP1 + mp * 65536, WeP1 + mp * 8192,
        OB + (size_t)mp * 1024 * 256);
  }

  final_kernel<<<1024, 64, 0, stream>>>(OB, Wa, va, Wfc, bfc, out);
}

// Round 7
// 484.689 us; speedup vs baseline: 1.9259x; 1.9259x over previous
//
#include <hip/hip_runtime.h>
#include <hip/hip_bf16.h>

// HINGCN_GS — bf16 MFMA implementation.
// PF = relu(feats @ Wprep) for all nodes (bf16, computed once).
// Per metapath:
//   msg_kernel<0>: fused [gathered PF | gathered edge_emb] @ [Wn0;We0]  (M=112640,K=160)
//                  + slf fragment (PF_center @ Ws0) + relu/mean/add/relu -> G bf16 [11264,288]
//   edge_kernel:   [G0rep | G1 | ed0] @ Wedge  (K=544,N=32) -> G cols 256..287 (EDU)
//   msg_kernel<1>: [G1|EDU] @ [Wn1;We1] (K=288) + slf (G0 @ Ws1) -> OB f32
// final_kernel: metapath attention + normalize + logits (f32).
// MFMA 16x16x32_bf16 layouts: A row=l&15, k=(l>>4)*8+e ; B col=l&15, same k;
// C/D col=l&15, row=(l>>4)*4+reg (guide §3, m89/m91-verified).

typedef __attribute__((ext_vector_type(8))) short bf16x8;
typedef __attribute__((ext_vector_type(4))) short short4v;
typedef __attribute__((ext_vector_type(4))) float f32x4;

#define DEV __device__ __forceinline__

DEV short f2b(float x) {
  __hip_bfloat16 h = __float2bfloat16(x);
  return *reinterpret_cast<short*>(&h);
}
DEV float b2f(short s) {
  unsigned u = ((unsigned)(unsigned short)s) << 16;
  return __builtin_bit_cast(float, u);
}
DEV bf16x8 cvt8(float4 f0, float4 f1) {
  bf16x8 a;
  a[0] = f2b(f0.x); a[1] = f2b(f0.y); a[2] = f2b(f0.z); a[3] = f2b(f0.w);
  a[4] = f2b(f1.x); a[5] = f2b(f1.y); a[6] = f2b(f1.z); a[7] = f2b(f1.w);
  return a;
}
DEV int idxcomb(int gr, const int* ids, const int* n0, const int* n1) {
  return (gr < 1024) ? ids[gr] : (gr < 11264) ? n0[gr - 1024] : n1[gr - 11264];
}
DEV int ecomb(int gr, const int* e0, const int* e1) {  // gr >= 1024
  return (gr < 11264) ? e0[gr - 1024] : e1[gr - 11264];
}

// ---------- one-time weight pack: bf16, MFMA-fragment-linear ----------
// Bp[((kt*NF+nf)*64 + l)*8 + e] = W[kt*32 + (l>>4)*8 + e][nf*16 + (l&15)]
__global__ __launch_bounds__(256) void pack_kernel(
    const float* __restrict__ Wprep,
    const float* __restrict__ Ws0, const float* __restrict__ Wn0, const float* __restrict__ We0,
    const float* __restrict__ Ws1, const float* __restrict__ Wn1, const float* __restrict__ We1,
    const float* __restrict__ Wedge, short* __restrict__ WP)
{
  int i = blockIdx.x * 256 + threadIdx.x;
  if (i >= 477184) return;
  float v;
  if (i < 16384) {  // Wprep: KT=4, NF=8, N=128
    int kt = i >> 12, rr = i & 4095;
    int nf = rr >> 9, q = rr & 511, l = q >> 3, e = q & 7;
    int k = kt * 32 + (l >> 4) * 8 + e, n = nf * 16 + (l & 15);
    v = Wprep[k * 128 + n];
  } else {
    int j = i - 16384;
    int mp = j / 230400, r = j % 230400;
    if (r < 212992) {  // NF=16 buffers, chunk 8192/kt
      int r2, sel;
      if (r < 40960)       { r2 = r;          sel = 0; }   // W0cat [Wn0;We0] KT=5
      else if (r < 73728)  { r2 = r - 40960;  sel = 1; }   // Ws0 KT=4
      else if (r < 147456) { r2 = r - 73728;  sel = 2; }   // W1cat [Wn1;We1] KT=9
      else                 { r2 = r - 147456; sel = 3; }   // Ws1 KT=8
      int kt = r2 >> 13, rr = r2 & 8191;
      int nf = rr >> 9, q = rr & 511, l = q >> 3, e = q & 7;
      int k = kt * 32 + (l >> 4) * 8 + e, col = nf * 16 + (l & 15);
      int h = col >> 5, o = col & 31;
      if (sel == 0) v = (k < 128) ? Wn0[(((size_t)mp * 8 + h) * 128 + k) * 32 + o]
                                  : We0[(((size_t)mp * 8 + h) * 32 + (k - 128)) * 32 + o];
      else if (sel == 1) v = Ws0[(((size_t)mp * 8 + h) * 128 + k) * 32 + o];
      else if (sel == 2) v = (k < 256) ? Wn1[(((size_t)mp * 8 + h) * 256 + k) * 32 + o]
                                       : We1[(((size_t)mp * 8 + h) * 32 + (k - 256)) * 32 + o];
      else v = Ws1[(((size_t)mp * 8 + h) * 256 + k) * 32 + o];
    } else {  // Wedge KT=17, NF=2
      int r2 = r - 212992;
      int kt = r2 >> 10, rr = r2 & 1023;
      int nf = rr >> 9, q = rr & 511, l = q >> 3, e = q & 7;
      int k = kt * 32 + (l >> 4) * 8 + e, n = nf * 16 + (l & 15);
      v = Wedge[((size_t)mp * 544 + k) * 32 + n];
    }
  }
  WP[i] = f2b(v);
}

// ---------- PF = relu(feats @ Wprep), bf16 out [100000,128] ----------
__global__ __launch_bounds__(256) void pf_kernel(
    const float* __restrict__ feats, const short* __restrict__ Bp, short* __restrict__ PF)
{
  int t = threadIdx.x, w = t >> 6, l = t & 63;
  int lr = l & 15, lk = l >> 4;
  int r0 = blockIdx.x * 64 + w * 16;
  int arow = min(r0 + lr, 99999);
  const float* abase = feats + (size_t)arow * 128 + lk * 8;
  f32x4 acc[8];
#pragma unroll
  for (int j = 0; j < 8; ++j) acc[j] = (f32x4){0.f, 0.f, 0.f, 0.f};
#pragma unroll
  for (int kt = 0; kt < 4; ++kt) {
    float4 f0 = *(const float4*)(abase + kt * 32);
    float4 f1 = *(const float4*)(abase + kt * 32 + 4);
    bf16x8 a = cvt8(f0, f1);
#pragma unroll
    for (int j = 0; j < 8; ++j) {
      bf16x8 b = *(const bf16x8*)(Bp + ((size_t)(kt * 8 + j) * 64 + l) * 8);
      acc[j] = __builtin_amdgcn_mfma_f32_16x16x32_bf16(a, b, acc[j], 0, 0, 0);
    }
  }
#pragma unroll
  for (int j = 0; j < 8; ++j)
#pragma unroll
    for (int rg = 0; rg < 4; ++rg) {
      int row = r0 + lk * 4 + rg;
      if (row < 100000)
        PF[(size_t)row * 128 + j * 16 + lr] = f2b(fmaxf(acc[j][rg], 0.f));
    }
}

// ---------- fused msg + slf + mean kernel ----------
// V=0: layer0 (A gathered from PF + edge_emb), out -> G bf16 stride 288
// V=1: layer1 (A = G rows 1024.., K=288),      out -> OB f32 stride 256
template<int V>
__global__ __launch_bounds__(256) void msg_kernel(
    const short* __restrict__ PF, const short* __restrict__ G,
    const int* __restrict__ ids, const int* __restrict__ n0, const int* __restrict__ n1,
    const int* __restrict__ e0, const int* __restrict__ e1,
    const float* __restrict__ ee,
    const short* __restrict__ Bmsg, const short* __restrict__ Bslf,
    short* __restrict__ Gout, float* __restrict__ OB)
{
  constexpr int KT = V ? 9 : 5;
  constexpr int SKT = V ? 8 : 4;
  __shared__ short mst[256][88];   // column-major msg stage (row stride 176B, 16B-aligned)
  __shared__ float sst[8][260];    // slf stage
  int t = threadIdx.x, w = t >> 6, l = t & 63;
  int lr = l & 15, lk = l >> 4;
  int blk = blockIdx.x;

  const short* abase[5];
  int eid[5];
  if constexpr (V == 0) {
#pragma unroll
    for (int mf = 0; mf < 5; ++mf) {
      int gr = 1024 + blk * 80 + mf * 16 + lr;
      int nid = idxcomb(gr, ids, n0, n1);
      abase[mf] = PF + (size_t)nid * 128 + lk * 8;
      eid[mf] = ecomb(gr, e0, e1);
    }
  } else {
#pragma unroll
    for (int mf = 0; mf < 5; ++mf) {
      int r = blk * 80 + mf * 16 + lr;
      abase[mf] = G + (size_t)(1024 + r) * 288 + lk * 8;
    }
  }
  const short* sbase;
  {
    int grp = min(blk * 8 + lr, V ? 1023 : 11263);
    if constexpr (V == 0) {
      int nid = idxcomb(grp, ids, n0, n1);
      sbase = PF + (size_t)nid * 128 + lk * 8;
    } else {
      sbase = G + (size_t)grp * 288 + lk * 8;
    }
  }

  f32x4 acc[5][4], sacc[4];
#pragma unroll
  for (int mf = 0; mf < 5; ++mf)
#pragma unroll
    for (int j = 0; j < 4; ++j) acc[mf][j] = (f32x4){0.f, 0.f, 0.f, 0.f};
#pragma unroll
  for (int j = 0; j < 4; ++j) sacc[j] = (f32x4){0.f, 0.f, 0.f, 0.f};

#pragma unroll
  for (int kt = 0; kt < KT; ++kt) {
    bf16x8 a[5];
    if (V == 0 && kt == 4) {
#pragma unroll
      for (int mf = 0; mf < 5; ++mf) {
        const float* ep = ee + (size_t)eid[mf] * 32 + lk * 8;
        a[mf] = cvt8(*(const float4*)ep, *(const float4*)(ep + 4));
      }
    } else {
#pragma unroll
      for (int mf = 0; mf < 5; ++mf) a[mf] = *(const bf16x8*)(abase[mf] + kt * 32);
    }
#pragma unroll
    for (int j = 0; j < 4; ++j) {
      bf16x8 b = *(const bf16x8*)(Bmsg + ((size_t)(kt * 16 + w * 4 + j) * 64 + l) * 8);
#pragma unroll
      for (int mf = 0; mf < 5; ++mf)
        acc[mf][j] = __builtin_amdgcn_mfma_f32_16x16x32_bf16(a[mf], b, acc[mf][j], 0, 0, 0);
    }
    if (kt < SKT) {
      bf16x8 as = *(const bf16x8*)(sbase + kt * 32);
#pragma unroll
      for (int j = 0; j < 4; ++j) {
        bf16x8 b = *(const bf16x8*)(Bslf + ((size_t)(kt * 16 + w * 4 + j) * 64 + l) * 8);
        sacc[j] = __builtin_amdgcn_mfma_f32_16x16x32_bf16(as, b, sacc[j], 0, 0, 0);
      }
    }
  }

  // stage msg (relu -> bf16), column-major: lane's 4 regs = 4 consecutive rows
#pragma unroll
  for (int mf = 0; mf < 5; ++mf)
#pragma unroll
    for (int j = 0; j < 4; ++j) {
      int col = (w * 4 + j) * 16 + lr;
      short4v pk;
#pragma unroll
      for (int rg = 0; rg < 4; ++rg) pk[rg] = f2b(fmaxf(acc[mf][j][rg], 0.f));
      *(short4v*)&mst[col][mf * 16 + lk * 4] = pk;
    }
  if (lk < 2) {
#pragma unroll
    for (int j = 0; j < 4; ++j) {
      int col = (w * 4 + j) * 16 + lr;
#pragma unroll
      for (int rg = 0; rg < 4; ++rg) sst[lk * 4 + rg][col] = sacc[j][rg];
    }
  }
  __syncthreads();

  // reduce: thread t owns column t; rows 0..79 contiguous -> 10x b128 reads
  float gs[8];
#pragma unroll
  for (int g = 0; g < 8; ++g) gs[g] = 0.f;
#pragma unroll
  for (int c8 = 0; c8 < 10; ++c8) {
    bf16x8 v = *(const bf16x8*)&mst[t][c8 * 8];
#pragma unroll
    for (int e = 0; e < 8; ++e) gs[(c8 * 8 + e) / 10] += b2f(v[e]);
  }
  if constexpr (V == 0) {
#pragma unroll
    for (int g = 0; g < 8; ++g) {
      float x = fmaxf(sst[g][t] + 0.1f * gs[g], 0.f);
      Gout[(size_t)(blk * 8 + g) * 288 + t] = f2b(x);
    }
  } else {
#pragma unroll
    for (int g = 0; g < 8; ++g) {
      float x = fmaxf(sst[g][t] + 0.1f * gs[g], 0.f);
      OB[(size_t)(blk * 8 + g) * 256 + t] = x;
    }
  }
}

// ---------- edge update: EDU = relu([G0rep|G1|ed0] @ Wedge) -> G cols 256..287 ----------
__global__ __launch_bounds__(256) void edge_kernel(
    const short* __restrict__ G, const float* __restrict__ ee,
    const int* __restrict__ e0, const short* __restrict__ Bp, short* __restrict__ Gw)
{
  int t = threadIdx.x, w = t >> 6, l = t & 63;
  int lr = l & 15, lk = l >> 4;
  int gr = blockIdx.x * 64 + w * 16 + lr;    // 0..10239
  const short* a0 = G + (size_t)(gr / 10) * 288 + lk * 8;
  const short* a1 = G + (size_t)(1024 + gr) * 288 + lk * 8;
  int eid = e0[gr];
  f32x4 acc[2];
  acc[0] = (f32x4){0.f, 0.f, 0.f, 0.f}; acc[1] = (f32x4){0.f, 0.f, 0.f, 0.f};
#pragma unroll
  for (int kt = 0; kt < 17; ++kt) {
    bf16x8 a;
    if (kt < 8)        a = *(const bf16x8*)(a0 + kt * 32);
    else if (kt < 16)  a = *(const bf16x8*)(a1 + (kt - 8) * 32);
    else {
      const float* ep = ee + (size_t)eid * 32 + lk * 8;
      a = cvt8(*(const float4*)ep, *(const float4*)(ep + 4));
    }
#pragma unroll
    for (int j = 0; j < 2; ++j) {
      bf16x8 b = *(const bf16x8*)(Bp + ((size_t)(kt * 2 + j) * 64 + l) * 8);
      acc[j] = __builtin_amdgcn_mfma_f32_16x16x32_bf16(a, b, acc[j], 0, 0, 0);
    }
  }
  int rb = blockIdx.x * 64 + w * 16;
#pragma unroll
  for (int j = 0; j < 2; ++j)
#pragma unroll
    for (int rg = 0; rg < 4; ++rg) {
      int row = rb + lk * 4 + rg;
      Gw[(size_t)(1024 + row) * 288 + 256 + j * 16 + lr] = f2b(fmaxf(acc[j][rg], 0.f));
    }
}

// ---------- metapath attention + normalize + logits ----------
__global__ __launch_bounds__(64) void final_kernel(
    const float* __restrict__ outb, const float* __restrict__ Wa,
    const float* __restrict__ va, const float* __restrict__ Wfc,
    const float* __restrict__ bfc, float* __restrict__ dout)
{
  __shared__ float aggv[256];
  int t = threadIdx.x;
  int n = blockIdx.x;
  const float* o0 = outb + (size_t)n * 256;
  const float* o1 = outb + (size_t)(1024 + n) * 256;
  float s[2];
#pragma unroll
  for (int mp = 0; mp < 2; ++mp) {
    const float* o = mp ? o1 : o0;
    float a = 0.f;
    for (int k = 0; k < 256; ++k) a = fmaf(o[k], Wa[k * 64 + t], a);
    float v = tanhf(a) * va[t];
#pragma unroll
    for (int msk = 32; msk; msk >>= 1) v += __shfl_xor(v, msk, 64);
    s[mp] = v;
  }
  float mx = fmaxf(s[0], s[1]);
  float ex0 = expf(s[0] - mx), ex1 = expf(s[1] - mx);
  float ise = 1.f / (ex0 + ex1);
  float w0 = ex0 * ise, w1 = ex1 * ise;
  float ss = 0.f;
  for (int k = t; k < 256; k += 64) {
    float av = fmaf(w0, o0[k], w1 * o1[k]);
    aggv[k] = av;
    ss = fmaf(av, av, ss);
  }
#pragma unroll
  for (int msk = 32; msk; msk >>= 1) ss += __shfl_xor(ss, msk, 64);
  float inv = 1.f / fmaxf(sqrtf(ss), 1e-12f);
  __syncthreads();
  if (t < 8) {
    float lg = bfc[t];
    for (int k = 0; k < 256; ++k) lg = fmaf(aggv[k] * inv, Wfc[k * 8 + t], lg);
    dout[(size_t)n * 8 + t] = lg;
  }
  if (t == 0) {
    dout[8192 + n] = w0;
    dout[8192 + 1024 + n] = w1;
  }
}

extern "C" void kernel_launch(void* const* d_in, const int* in_sizes, int n_in,
                              void* d_out, int out_size, void* d_ws, size_t ws_size,
                              hipStream_t stream) {
  (void)in_sizes; (void)n_in; (void)out_size;
  const int* ids = (const int*)d_in[0];
  const int* n0a[2] = {(const int*)d_in[1], (const int*)d_in[5]};
  const int* e0a[2] = {(const int*)d_in[2], (const int*)d_in[6]};
  const int* n1a[2] = {(const int*)d_in[3], (const int*)d_in[7]};
  const int* e1a[2] = {(const int*)d_in[4], (const int*)d_in[8]};
  const float* feats = (const float*)d_in[9];
  const float* eea[2] = {(const float*)d_in[10], (const float*)d_in[11]};
  const float* Wprep  = (const float*)d_in[12];
  const float* Ws0    = (const float*)d_in[13];
  const float* Wn0    = (const float*)d_in[14];
  const float* We0    = (const float*)d_in[15];
  const float* Ws1    = (const float*)d_in[16];
  const float* Wn1    = (const float*)d_in[17];
  const float* We1    = (const float*)d_in[18];
  const float* Wedge0 = (const float*)d_in[19];
  const float* Wa     = (const float*)d_in[20];
  const float* va     = (const float*)d_in[21];
  const float* Wfc    = (const float*)d_in[22];
  const float* bfc    = (const float*)d_in[23];
  float* out = (float*)d_out;

  char* wb = (char*)d_ws;
  float* OB = (float*)wb;                                   // 2*1024*256*4 = 2,097,152 B
  short* PF = (short*)(wb + 2097152);                       // 100000*128*2 = 25,600,000 B
  short* G  = (short*)(wb + 2097152 + 25600000);            // 11264*288*2 = 6,488,064 B
  short* WP = (short*)(wb + 2097152 + 25600000 + 6488064);  // 477184*2    =    954,368 B
  if (ws_size < (size_t)35139584) return;

  pack_kernel<<<1865, 256, 0, stream>>>(Wprep, Ws0, Wn0, We0, Ws1, Wn1, We1, Wedge0, WP);
  pf_kernel<<<1563, 256, 0, stream>>>(feats, WP, PF);

  for (int mp = 0; mp < 2; ++mp) {
    short* mb = WP + 16384 + (size_t)mp * 230400;
    short* W0cat = mb;            // KT=5, NF=16
    short* Ws0p  = mb + 40960;    // KT=4
    short* W1cat = mb + 73728;    // KT=9
    short* Ws1p  = mb + 147456;   // KT=8
    short* Wedgp = mb + 212992;   // KT=17, NF=2
    msg_kernel<0><<<1408, 256, 0, stream>>>(
        PF, nullptr, ids, n0a[mp], n1a[mp], e0a[mp], e1a[mp], eea[mp],
        W0cat, Ws0p, G, nullptr);
    edge_kernel<<<160, 256, 0, stream>>>(G, eea[mp], e0a[mp], Wedgp, G);
    msg_kernel<1><<<128, 256, 0, stream>>>(
        nullptr, G, nullptr, nullptr, nullptr, nullptr, nullptr, nullptr,
        W1cat, Ws1p, nullptr, OB + (size_t)mp * 1024 * 256);
  }

  final_kernel<<<1024, 64, 0, stream>>>(OB, Wa, va, Wfc, bfc, out);
}